// Round 8
// baseline (167.487 us; speedup 1.0000x reference)
//
#include <hip/hip_runtime.h>
#include <stdint.h>

// All I/O fp32. MFMA bf16: weights as A-operand (A[m=out][k]), activations as
// B (B[k][n=point]); next layer's weights pre-permuted along input dim
// (P(k)=4*(k>>3)+(k&3)+16*((k>>2)&1)) so layer->layer handoff is in-lane packs.
// R8: chain-latency amortization by ILP. R3/R5/R7 all plateau at 42-48 us with
// every pipe <25% busy -> the 11-stage serial chain per 16 points is the floor.
// Now 64 points/wave (4 independent groups): each stage = 4 independent MFMAs,
// shared weight+bias frags read once from LDS per stage. IT=1 straight-line,
// 1024 blocks (4/CU), LDS = 40 KiB exactly (frags + biases).

typedef __attribute__((ext_vector_type(8))) __bf16 bf16x8;
typedef __attribute__((ext_vector_type(4))) float f32x4;

union FragU { uint32_t u[4]; bf16x8 v; uint4 q; };

__device__ __forceinline__ unsigned short f2bf(float f) {
    union { float f; uint32_t i; } v; v.f = f;
    return (unsigned short)((v.i + 0x7FFFu + ((v.i >> 16) & 1u)) >> 16); // RTNE (prep only)
}
// fast pack: lo16 = bf16(x), hi16 = bf16(y); round-half-up (3 VALU)
__device__ __forceinline__ uint32_t pk2f(float x, float y) {
    union { float f; uint32_t i; } a, b; a.f = x; b.f = y;
    return __builtin_amdgcn_perm(b.i + 0x8000u, a.i + 0x8000u, 0x07060302u);
}
__device__ __forceinline__ float bits2f(uint32_t u) {
    union { uint32_t i; float f; } v; v.i = u; return v.f;
}
__device__ __forceinline__ int permK(int k) {
    return 4 * (k >> 3) + (k & 3) + 16 * ((k >> 2) & 1);
}
__device__ __forceinline__ f32x4 MF(bf16x8 a, bf16x8 b, f32x4 c) {
    return __builtin_amdgcn_mfma_f32_16x16x32_bf16(a, b, c, 0, 0, 0);
}

// ws dword layout (10240 dwords):
//   [0,1024)    layer0 A-frags  [chunk(2)][tile(2)][lane(64)][dw(4)]  (K=60 pad 64)
//   [1024,3072) layers1-4 A     [L(4)][tile(2)][lane][dw]             (perm k)
//   [3072,3328) layer5 A        [lane][dw]                            (perm k, m>=8 zero)
//   [3328,7424) bank A          [k(8)][tile(2)][lane][dw]
//   [7424,9984) bias L0-4 fp32  [L(5)][tile(2)][lane][r(4)]
//   [9984,10240) bias L5 fp32   [lane][r]                             (m>=8 zero)

struct WPf { const float* p[13]; };

__global__ void pc_prep(WPf wp, uint32_t* __restrict__ ws) {
    int idx = blockIdx.x * blockDim.x + threadIdx.x;
    if (idx >= 10240) return;
    if (idx < 7424) {
        int layer, t, chunk = 0, lane, d; const float* w; bool perm;
        int r = idx;
        if (r < 1024) { chunk = r >> 9; r &= 511; t = r >> 8; r &= 255; lane = r >> 2; d = r & 3;
                        layer = 0; w = wp.p[0]; perm = false; }
        else if (r < 3072) { r -= 1024; layer = 1 + (r >> 9); r &= 511; t = r >> 8; r &= 255;
                             lane = r >> 2; d = r & 3; w = wp.p[2 * layer]; perm = true; }
        else if (r < 3328) { r -= 3072; layer = 5; t = 0; lane = r >> 2; d = r & 3;
                             w = wp.p[10]; perm = true; }
        else { r -= 3328; int bk = r >> 9; r &= 511; t = r >> 8; r &= 255; lane = r >> 2; d = r & 3;
               layer = -1; w = wp.p[12] + bk * 1024; perm = false; }
        int gq = lane >> 4, m = t * 16 + (lane & 15);
        uint32_t o = 0;
        #pragma unroll
        for (int e = 0; e < 2; ++e) {
            int kf = 8 * gq + 2 * d + e;
            float v = 0.f;
            if (layer == -1) {
                v = w[kf * 32 + m];                       // bank: A[m=o][k=i] = bank[k][i*32+o]
            } else {
                int ks = perm ? permK(kf) : (chunk * 32 + kf);
                if (layer == 0)      { if (ks < 60) v = w[ks * 32 + m]; }
                else if (layer == 5) { if (m < 8)   v = w[ks * 8 + m]; }
                else                 v = w[ks * 32 + m];  // A[m][k] = W[P(k)][m]
            }
            o |= ((uint32_t)f2bf(v)) << (16 * e);
        }
        ws[idx] = o;
    } else if (idx < 9984) {
        int r = idx - 7424; int L = r >> 9; r &= 511; int t = r >> 8; r &= 255;
        int lane = r >> 2, rr = r & 3;
        ((float*)ws)[idx] = wp.p[2 * L + 1][t * 16 + 4 * (lane >> 4) + rr];
    } else {
        int r = idx - 9984; int lane = r >> 2, rr = r & 3;
        int m = 4 * (lane >> 4) + rr;
        ((float*)ws)[idx] = (m < 8) ? wp.p[11][m] : 0.f;
    }
}

__global__ __launch_bounds__(256, 4) void pc_main(
    const float* __restrict__ rel, const float* __restrict__ feat,
    const uint32_t* __restrict__ wsu, float* __restrict__ out)
{
    __shared__ __align__(16) uint32_t W[10240];   // 40 KiB: all frags + biases
    {
        uint4* s4 = (uint4*)W;
        const uint4* g4 = (const uint4*)wsu;
        #pragma unroll
        for (int i = 0; i < 10; ++i) s4[threadIdx.x + 256 * i] = g4[threadIdx.x + 256 * i];
    }
    __syncthreads();

    const int lane = threadIdx.x & 63;
    const int wv = threadIdx.x >> 6;
    const int g = lane >> 4;
    const int n16 = lane & 15;

    #define LDF(off) ({ FragU _f; _f.q = ((const uint4*)(W + (off)))[lane]; _f.v; })
    #define LDB(off) ({ float4 _b = ((const float4*)(W + (off)))[lane]; \
                        (f32x4){_b.x, _b.y, _b.z, _b.w}; })

    const size_t base = (size_t)(blockIdx.x * 4 + wv) * 64;

    // ---- load + pack inputs for 4 groups (independent loads, early issue) ----
    FragU b0[4], b1[4], bf_[4];
    #pragma unroll
    for (int q = 0; q < 4; ++q) {
        const size_t n = base + q * 16 + n16;
        const float* rrow = rel + n * 60;
        float4 ra = *(const float4*)(rrow + 8 * g);
        float4 rb = *(const float4*)(rrow + 8 * g + 4);
        float4 rc = *(const float4*)(rrow + 32 + 8 * g);
        float4 rd = make_float4(0.f, 0.f, 0.f, 0.f);
        if (g < 3) rd = *(const float4*)(rrow + 36 + 8 * g);
        const float* frow = feat + n * 32 + 8 * g;
        float4 fa = *(const float4*)frow;
        float4 fb = *(const float4*)(frow + 4);
        b0[q].u[0] = pk2f(ra.x, ra.y); b0[q].u[1] = pk2f(ra.z, ra.w);
        b0[q].u[2] = pk2f(rb.x, rb.y); b0[q].u[3] = pk2f(rb.z, rb.w);
        b1[q].u[0] = pk2f(rc.x, rc.y); b1[q].u[1] = pk2f(rc.z, rc.w);
        b1[q].u[2] = pk2f(rd.x, rd.y); b1[q].u[3] = pk2f(rd.z, rd.w);
        bf_[q].u[0] = pk2f(fa.x, fa.y); bf_[q].u[1] = pk2f(fa.z, fa.w);
        bf_[q].u[2] = pk2f(fb.x, fb.y); bf_[q].u[3] = pk2f(fb.z, fb.w);
    }

    // ---- layer 0: shared frags/bias read once, 4 independent MFMA streams ----
    f32x4 t0[4], t1[4];
    {
        bf16x8 w00 = LDF(0), w01 = LDF(256), w10 = LDF(512), w11 = LDF(768);
        f32x4 c0 = LDB(7424), c1 = LDB(7424 + 256);
        #pragma unroll
        for (int q = 0; q < 4; ++q) {
            t0[q] = MF(w00, b0[q].v, c0); t1[q] = MF(w01, b0[q].v, c1);
            t0[q] = MF(w10, b1[q].v, t0[q]); t1[q] = MF(w11, b1[q].v, t1[q]);
        }
    }

    // ---- layers 1..4 ----
    #pragma unroll
    for (int L = 0; L < 4; ++L) {
        bf16x8 wa = LDF(1024 + L * 512), wb = LDF(1024 + L * 512 + 256);
        f32x4 ca = LDB(7424 + (L + 1) * 512), cb = LDB(7424 + (L + 1) * 512 + 256);
        #pragma unroll
        for (int q = 0; q < 4; ++q) {
            FragU bx;
            #pragma unroll
            for (int r = 0; r < 4; ++r) {
                t0[q][r] = fmaxf(t0[q][r], 0.01f * t0[q][r]);
                t1[q][r] = fmaxf(t1[q][r], 0.01f * t1[q][r]);
            }
            bx.u[0] = pk2f(t0[q][0], t0[q][1]); bx.u[1] = pk2f(t0[q][2], t0[q][3]);
            bx.u[2] = pk2f(t1[q][0], t1[q][1]); bx.u[3] = pk2f(t1[q][2], t1[q][3]);
            t0[q] = MF(wa, bx.v, ca);
            t1[q] = MF(wb, bx.v, cb);
        }
    }

    // ---- layer 5 (32->8) ----
    {
        bf16x8 w5 = LDF(3072);
        f32x4 c5 = LDB(9984);
        #pragma unroll
        for (int q = 0; q < 4; ++q) {
            FragU bx;
            #pragma unroll
            for (int r = 0; r < 4; ++r) {
                t0[q][r] = fmaxf(t0[q][r], 0.01f * t0[q][r]);
                t1[q][r] = fmaxf(t1[q][r], 0.01f * t1[q][r]);
            }
            bx.u[0] = pk2f(t0[q][0], t0[q][1]); bx.u[1] = pk2f(t0[q][2], t0[q][3]);
            bx.u[2] = pk2f(t1[q][0], t1[q][1]); bx.u[3] = pk2f(t1[q][2], t1[q][3]);
            t0[q] = MF(w5, bx.v, c5);   // logits m0..3 in g=0, m4..7 in g=1
        }
    }

    // ---- softmax per group (independent chains; coeffs kept bf16-packed) ----
    uint32_t cwp[4][4];
    #pragma unroll
    for (int q = 0; q < 4; ++q) {
        float m4 = fmaxf(fmaxf(t0[q][0], t0[q][1]), fmaxf(t0[q][2], t0[q][3]));
        float m8 = fmaxf(m4, __shfl_xor(m4, 16, 64));
        float e0 = __expf(t0[q][0] - m8), e1 = __expf(t0[q][1] - m8);
        float e2 = __expf(t0[q][2] - m8), e3 = __expf(t0[q][3] - m8);
        float s4 = e0 + e1 + e2 + e3;
        float s8 = s4 + __shfl_xor(s4, 16, 64);
        float inv = 1.0f / s8;
        uint32_t p01 = pk2f(e0 * inv, e1 * inv);
        uint32_t p23 = pk2f(e2 * inv, e3 * inv);
        cwp[q][0] = (uint32_t)__builtin_amdgcn_ds_bpermute(n16 * 4, (int)p01);
        cwp[q][1] = (uint32_t)__builtin_amdgcn_ds_bpermute(n16 * 4, (int)p23);
        cwp[q][2] = (uint32_t)__builtin_amdgcn_ds_bpermute((n16 + 16) * 4, (int)p01);
        cwp[q][3] = (uint32_t)__builtin_amdgcn_ds_bpermute((n16 + 16) * 4, (int)p23);
    }

    // ---- bank stage: k outer (16 shared frag reads), groups inner ----
    f32x4 o0[4], o1[4];
    #pragma unroll
    for (int q = 0; q < 4; ++q) {
        o0[q] = (f32x4){0.f, 0.f, 0.f, 0.f};
        o1[q] = (f32x4){0.f, 0.f, 0.f, 0.f};
    }
    #pragma unroll
    for (int k = 0; k < 8; ++k) {
        bf16x8 wk0 = LDF(3328 + k * 512), wk1 = LDF(3328 + k * 512 + 256);
        #pragma unroll
        for (int q = 0; q < 4; ++q) {
            f32x4 z = {0.f, 0.f, 0.f, 0.f};
            f32x4 u0 = MF(wk0, bf_[q].v, z);
            f32x4 u1 = MF(wk1, bf_[q].v, z);
            // cw_k: even k -> low half<<16, odd k -> high half masked (1 VALU)
            uint32_t pw = cwp[q][k >> 1];
            float ck = bits2f((k & 1) ? (pw & 0xFFFF0000u) : (pw << 16));
            #pragma unroll
            for (int r = 0; r < 4; ++r) {
                o0[q][r] += ck * u0[r];
                o1[q][r] += ck * u1[r];
            }
        }
    }

    #pragma unroll
    for (int q = 0; q < 4; ++q) {
        float* orow = out + (base + q * 16 + n16) * 32;
        *(float4*)(orow + 4 * g)      = make_float4(o0[q][0], o0[q][1], o0[q][2], o0[q][3]);
        *(float4*)(orow + 16 + 4 * g) = make_float4(o1[q][0], o1[q][1], o1[q][2], o1[q][3]);
    }
    #undef LDF
    #undef LDB
}

extern "C" void kernel_launch(void* const* d_in, const int* in_sizes, int n_in,
                              void* d_out, int out_size, void* d_ws, size_t ws_size,
                              hipStream_t stream)
{
    const float* rel = (const float*)d_in[0];
    const float* feat = (const float*)d_in[1];
    WPf wp;
    for (int i = 0; i < 13; ++i) wp.p[i] = (const float*)d_in[2 + i];
    uint32_t* ws = (uint32_t*)d_ws;
    float* out = (float*)d_out;

    const int npts = in_sizes[0] / 60;       // 262144
    const int nblocks = npts / 256;          // 1024 (4 waves x 64 pts)

    hipLaunchKernelGGL(pc_prep, dim3(40), dim3(256), 0, stream, wp, ws);
    hipLaunchKernelGGL(pc_main, dim3(nblocks), dim3(256), 0, stream, rel, feat, ws, out);
}